// Round 1
// baseline (3051.429 us; speedup 1.0000x reference)
//
#include <hip/hip_runtime.h>
#include <hip/hip_bf16.h>
#include <math.h>

#define S_LEN 256
#define B 32
#define E 512
#define H 512
#define G4 2048          // 4*H
#define T_TAGS 30
#define START_TAG 28
#define STOP_TAG 29

typedef unsigned short u16;
typedef unsigned int   u32;

__device__ __forceinline__ float bf2f(u16 u){
  u32 x = ((u32)u) << 16;
  return __uint_as_float(x);
}
__device__ __forceinline__ u16 f2bf(float f){
  u32 x = __float_as_uint(f);
  u32 r = (x + 0x7fffu + ((x >> 16) & 1u)) >> 16;
  return (u16)r;
}
__device__ __forceinline__ float sigf(float x){
  return 1.0f / (1.0f + __expf(-x));
}
__device__ __forceinline__ float tanh_fast(float x){
  // 1 - 2/(e^{2x}+1): saturates cleanly to +/-1 even when exp overflows to inf
  return 1.0f - 2.0f / (__expf(2.0f * x) + 1.0f);
}

// ---------------- init: h0 -> h parity0, c0 -> c ----------------
__global__ void k_init(const float* __restrict__ h0, const float* __restrict__ c0,
                       float* __restrict__ h_prev, float* __restrict__ c_st){
  int i = blockIdx.x * blockDim.x + threadIdx.x;   // 2*B*H = 32768 total
  if (i < 2 * B * H){ h_prev[i] = h0[i]; c_st[i] = c0[i]; }
}

// ---------------- phase A: xw[dir][s*B+b][g] = emb[sent] @ w_ih^T + b_ih + b_hh (bf16 out) ----
#define BM 128
#define BN 128
#define BK 16
__global__ __launch_bounds__(256) void k_gemm_xw(
    const int* __restrict__ sent, const float* __restrict__ emb,
    const float* __restrict__ w_ih_f, const float* __restrict__ w_ih_b,
    const float* __restrict__ b_ih_f, const float* __restrict__ b_hh_f,
    const float* __restrict__ b_ih_b, const float* __restrict__ b_hh_b,
    u16* __restrict__ xw)
{
  int dir = blockIdx.z;
  const float* W  = dir ? w_ih_b : w_ih_f;
  const float* bi = dir ? b_ih_b : b_ih_f;
  const float* bh = dir ? b_hh_b : b_hh_f;
  int m0 = blockIdx.y * BM;
  int n0 = blockIdx.x * BN;
  int tid = threadIdx.x;

  __shared__ float As[BK][BM + 4];
  __shared__ float Ws[BK][BN + 4];
  __shared__ int   idx_s[BM];

  if (tid < BM) idx_s[tid] = sent[m0 + tid];

  float acc[8][8] = {};
  int ty = tid >> 4, tx = tid & 15;     // 16x16 thread grid, 8x8 micro-tile

  for (int kt = 0; kt < E; kt += BK){
    __syncthreads();
    int row = tid >> 2;              // 0..63
    int kq  = (tid & 3) << 2;        // 0,4,8,12
    #pragma unroll
    for (int hh = 0; hh < 2; ++hh){
      int rr = row + hh * 64;
      float4 av = *reinterpret_cast<const float4*>(emb + (size_t)idx_s[rr] * E + kt + kq);
      As[kq+0][rr] = av.x; As[kq+1][rr] = av.y; As[kq+2][rr] = av.z; As[kq+3][rr] = av.w;
      float4 wv = *reinterpret_cast<const float4*>(W + (size_t)(n0 + rr) * E + kt + kq);
      Ws[kq+0][rr] = wv.x; Ws[kq+1][rr] = wv.y; Ws[kq+2][rr] = wv.z; Ws[kq+3][rr] = wv.w;
    }
    __syncthreads();
    #pragma unroll
    for (int k = 0; k < BK; ++k){
      float a[8], bb[8];
      float4 a0 = *reinterpret_cast<const float4*>(&As[k][ty*8]);
      float4 a1 = *reinterpret_cast<const float4*>(&As[k][ty*8+4]);
      float4 b0 = *reinterpret_cast<const float4*>(&Ws[k][tx*8]);
      float4 b1 = *reinterpret_cast<const float4*>(&Ws[k][tx*8+4]);
      a[0]=a0.x; a[1]=a0.y; a[2]=a0.z; a[3]=a0.w; a[4]=a1.x; a[5]=a1.y; a[6]=a1.z; a[7]=a1.w;
      bb[0]=b0.x; bb[1]=b0.y; bb[2]=b0.z; bb[3]=b0.w; bb[4]=b1.x; bb[5]=b1.y; bb[6]=b1.z; bb[7]=b1.w;
      #pragma unroll
      for (int i = 0; i < 8; ++i)
        #pragma unroll
        for (int j = 0; j < 8; ++j)
          acc[i][j] = fmaf(a[i], bb[j], acc[i][j]);
    }
  }
  // epilogue: add bias, convert to bf16, 16B stores
  #pragma unroll
  for (int i = 0; i < 8; ++i){
    int m = m0 + ty*8 + i;
    u16 out8[8];
    #pragma unroll
    for (int j = 0; j < 8; ++j){
      int n = n0 + tx*8 + j;
      float v = acc[i][j] + bi[n] + bh[n];
      out8[j] = f2bf(v);
    }
    u16* dst = xw + ((size_t)dir * 8192 + m) * G4 + n0 + tx*8;
    *reinterpret_cast<uint4*>(dst) = *reinterpret_cast<const uint4*>(out8);
  }
}

// ---------------- phase B: one LSTM step (both directions) ----------------
// 256 blocks: dir = bx>>7, slice = bx&127 -> j0 = slice*4 (4 h-dims per block, 16 gate rows)
// 256 threads: bp = tid&7 (4 batches each), r = (tid>>3)&15 (gate row), kh = tid>>7 (k half)
__global__ __launch_bounds__(256) void k_lstm_step(
    const float* __restrict__ w_hh_f, const float* __restrict__ w_hh_b,
    const u16* __restrict__ xw,
    const float* __restrict__ h_prev, float* __restrict__ h_next,
    float* __restrict__ c_st,
    float* __restrict__ hf, float* __restrict__ hb, int t)
{
  __shared__ float h_s[B][512];        // XOR-swizzled in 16B units
  __shared__ float w_s[16][516];
  __shared__ float gates2[2][16][32];  // [k-half][gate row][batch]

  int bx = blockIdx.x;
  int dir = bx >> 7;
  int slice = bx & 127;
  int j0 = slice << 2;
  const float* W = dir ? w_hh_b : w_hh_f;
  int tid = threadIdx.x;

  // stage h (all 32 batches x 512) with swizzle: col4 = k4 ^ ((b>>2)&7)
  const float* hsrc = h_prev + dir * (B * H);
  #pragma unroll
  for (int i = 0; i < 16; ++i){
    int fidx = (i * 256 + tid) << 2;           // 0..16380
    int b = fidx >> 9;
    int k = fidx & 511;
    float4 v = *reinterpret_cast<const float4*>(hsrc + fidx);
    int col4 = (k >> 2) ^ ((b >> 2) & 7);
    *reinterpret_cast<float4*>(&h_s[b][col4 << 2]) = v;
  }
  // stage 16 w_hh rows: row r -> global row (r>>2)*512 + j0 + (r&3)
  #pragma unroll
  for (int i = 0; i < 8; ++i){
    int fidx = (i * 256 + tid) << 2;           // 0..8188
    int r = fidx >> 9;
    int k = fidx & 511;
    int g = r >> 2, jr = r & 3;
    float4 v = *reinterpret_cast<const float4*>(W + (size_t)((g << 9) + j0 + jr) * H + k);
    *reinterpret_cast<float4*>(&w_s[r][k]) = v;
  }
  __syncthreads();

  int bp = tid & 7;
  int r  = (tid >> 3) & 15;
  int kh = tid >> 7;
  const float* wrow = w_s[r];
  int b0 = bp << 2;

  float acc0 = 0.f, acc1 = 0.f, acc2 = 0.f, acc3 = 0.f;
  int k4s = kh << 6;                 // 0 or 64 (in float4 units)
  #pragma unroll 4
  for (int k4 = k4s; k4 < k4s + 64; ++k4){
    int k = k4 << 2;
    float4 wv  = *reinterpret_cast<const float4*>(wrow + k);
    int cswz = (k4 ^ bp) << 2;
    float4 h0v = *reinterpret_cast<const float4*>(&h_s[b0 + 0][cswz]);
    float4 h1v = *reinterpret_cast<const float4*>(&h_s[b0 + 1][cswz]);
    float4 h2v = *reinterpret_cast<const float4*>(&h_s[b0 + 2][cswz]);
    float4 h3v = *reinterpret_cast<const float4*>(&h_s[b0 + 3][cswz]);
    acc0 = fmaf(wv.x,h0v.x,acc0); acc0 = fmaf(wv.y,h0v.y,acc0); acc0 = fmaf(wv.z,h0v.z,acc0); acc0 = fmaf(wv.w,h0v.w,acc0);
    acc1 = fmaf(wv.x,h1v.x,acc1); acc1 = fmaf(wv.y,h1v.y,acc1); acc1 = fmaf(wv.z,h1v.z,acc1); acc1 = fmaf(wv.w,h1v.w,acc1);
    acc2 = fmaf(wv.x,h2v.x,acc2); acc2 = fmaf(wv.y,h2v.y,acc2); acc2 = fmaf(wv.z,h2v.z,acc2); acc2 = fmaf(wv.w,h2v.w,acc2);
    acc3 = fmaf(wv.x,h3v.x,acc3); acc3 = fmaf(wv.y,h3v.y,acc3); acc3 = fmaf(wv.z,h3v.z,acc3); acc3 = fmaf(wv.w,h3v.w,acc3);
  }
  *reinterpret_cast<float4*>(&gates2[kh][r][b0]) = make_float4(acc0, acc1, acc2, acc3);
  __syncthreads();

  if (tid < 128){
    int jr2 = tid >> 5;       // 0..3
    int b   = tid & 31;
    int j   = j0 + jr2;
    int s_eff = dir ? (S_LEN - 1 - t) : t;
    const u16* xwp = xw + ((size_t)dir * 8192 + (size_t)s_eff * B + b) * G4;
    float iv = gates2[0][jr2     ][b] + gates2[1][jr2     ][b] + bf2f(xwp[j]);
    float fv = gates2[0][4  + jr2][b] + gates2[1][4  + jr2][b] + bf2f(xwp[512  + j]);
    float gv = gates2[0][8  + jr2][b] + gates2[1][8  + jr2][b] + bf2f(xwp[1024 + j]);
    float ov = gates2[0][12 + jr2][b] + gates2[1][12 + jr2][b] + bf2f(xwp[1536 + j]);
    size_t cidx = ((size_t)dir * B + b) * H + j;
    float c_old = c_st[cidx];
    float cn = sigf(fv) * c_old + sigf(iv) * tanh_fast(gv);
    float hn = sigf(ov) * tanh_fast(cn);
    c_st[cidx] = cn;
    h_next[cidx] = hn;
    float* hop = dir ? (hb + ((size_t)(S_LEN - 1 - t) * B + b) * H + j)
                     : (hf + ((size_t)t * B + b) * H + j);
    *hop = hn;
  }
}

// ---------------- phase C: feats[b][s][t] = [hf;hb] . w_out[t] + b_out[t] ----------------
__global__ __launch_bounds__(128) void k_feats(
    const float* __restrict__ hf, const float* __restrict__ hb,
    const float* __restrict__ w_out, const float* __restrict__ b_out,
    float* __restrict__ feats)
{
  int blk = blockIdx.x;             // s*B + b
  int s = blk >> 5, b = blk & 31;
  __shared__ float row[1024];
  __shared__ float part[T_TAGS][4];
  int tid = threadIdx.x;
  const float* hfp = hf + ((size_t)s * B + b) * H;
  const float* hbp = hb + ((size_t)s * B + b) * H;
  #pragma unroll
  for (int i = 0; i < 2; ++i){
    int f = (i * 128 + tid) << 2;   // 0..1020
    const float* src = (f < 512) ? (hfp + f) : (hbp + (f - 512));
    *reinterpret_cast<float4*>(&row[f]) = *reinterpret_cast<const float4*>(src);
  }
  __syncthreads();
  if (tid < 120){
    int tt = tid >> 2, p = tid & 3;
    const float* wrow = w_out + (size_t)tt * 1024 + p * 256;
    const float* rp = row + p * 256;
    float sum = 0.f;
    #pragma unroll 4
    for (int k = 0; k < 256; k += 4){
      float4 wv = *reinterpret_cast<const float4*>(wrow + k);
      float4 rv = *reinterpret_cast<const float4*>(rp + k);
      sum = fmaf(wv.x, rv.x, sum); sum = fmaf(wv.y, rv.y, sum);
      sum = fmaf(wv.z, rv.z, sum); sum = fmaf(wv.w, rv.w, sum);
    }
    part[tt][p] = sum;
  }
  __syncthreads();
  if (tid < T_TAGS){
    float v = part[tid][0] + part[tid][1] + part[tid][2] + part[tid][3] + b_out[tid];
    feats[((size_t)b * S_LEN + s) * T_TAGS + tid] = v;
  }
}

// ---------------- phase D: CRF forward + gold score, per batch element ----------------
__global__ __launch_bounds__(64) void k_crf(
    const float* __restrict__ feats, const float* __restrict__ trans,
    const int* __restrict__ tags, float* __restrict__ scores)
{
  int b = blockIdx.x;
  int tid = threadIdx.x;
  __shared__ float tr[T_TAGS][33];
  __shared__ float fv[32], fvn[32];
  for (int i = tid; i < T_TAGS * T_TAGS; i += 64) tr[i / T_TAGS][i % T_TAGS] = trans[i];
  if (tid < T_TAGS) fv[tid] = (tid == START_TAG) ? 0.f : -10000.f;
  __syncthreads();

  const float* fb = feats + (size_t)b * S_LEN * T_TAGS;
  for (int s = 0; s < S_LEN; ++s){
    if (tid < T_TAGS){
      float m = -1e30f;
      #pragma unroll
      for (int j = 0; j < T_TAGS; ++j) m = fmaxf(m, fv[j] + tr[tid][j]);
      float sum = 0.f;
      #pragma unroll
      for (int j = 0; j < T_TAGS; ++j) sum += __expf(fv[j] + tr[tid][j] - m);
      fvn[tid] = fb[s * T_TAGS + tid] + m + __logf(sum);
    }
    __syncthreads();
    if (tid < T_TAGS) fv[tid] = fvn[tid];
    __syncthreads();
  }

  float fsc = 0.f;
  if (tid == 0){
    float m = -1e30f;
    for (int i = 0; i < T_TAGS; ++i) m = fmaxf(m, fv[i] + tr[STOP_TAG][i]);
    float sum = 0.f;
    for (int i = 0; i < T_TAGS; ++i) sum += __expf(fv[i] + tr[STOP_TAG][i] - m);
    fsc = m + __logf(sum);
  }
  // gold score
  float g = 0.f;
  for (int s = tid; s < S_LEN; s += 64){
    int nxt = tags[s * B + b];
    int prv = (s == 0) ? START_TAG : tags[(s - 1) * B + b];
    g += tr[nxt][prv] + fb[s * T_TAGS + nxt];
  }
  #pragma unroll
  for (int o = 32; o > 0; o >>= 1) g += __shfl_down(g, o);
  if (tid == 0){
    int last = tags[(S_LEN - 1) * B + b];
    g += tr[STOP_TAG][last];
    scores[b] = fsc - g;
  }
}

__global__ void k_final(const float* __restrict__ scores, float* __restrict__ out){
  int tid = threadIdx.x;
  float v = (tid < B) ? scores[tid] : 0.f;
  #pragma unroll
  for (int o = 32; o > 0; o >>= 1) v += __shfl_down(v, o);
  if (tid == 0) out[0] = v;
}

// ---------------- host ----------------
extern "C" void kernel_launch(void* const* d_in, const int* in_sizes, int n_in,
                              void* d_out, int out_size, void* d_ws, size_t ws_size,
                              hipStream_t stream)
{
  const int*   sent   = (const int*)d_in[0];
  const int*   tags   = (const int*)d_in[1];
  const float* emb    = (const float*)d_in[2];
  const float* w_ih_f = (const float*)d_in[3];
  const float* w_hh_f = (const float*)d_in[4];
  const float* b_ih_f = (const float*)d_in[5];
  const float* b_hh_f = (const float*)d_in[6];
  const float* w_ih_b = (const float*)d_in[7];
  const float* w_hh_b = (const float*)d_in[8];
  const float* b_ih_b = (const float*)d_in[9];
  const float* b_hh_b = (const float*)d_in[10];
  const float* w_out  = (const float*)d_in[11];
  const float* b_out  = (const float*)d_in[12];
  const float* trans  = (const float*)d_in[13];
  const float* h0     = (const float*)d_in[14];
  const float* c0     = (const float*)d_in[15];

  // ws layout (bytes)
  const size_t OFF_XW    = 0;                      // bf16 [2][8192][2048]  = 64 MiB
  const size_t OFF_HF    = 67108864;               // f32  [256][32][512]   = 16 MiB
  const size_t OFF_HB    = 83886080;               // f32  [256][32][512]   = 16 MiB
  const size_t OFF_HDB   = 100663296;              // f32  [2][2][32][512]  = 256 KiB (parity double buffer)
  const size_t OFF_C     = 100925440;              // f32  [2][32][512]     = 128 KiB
  const size_t OFF_FEATS = 101056512;              // f32  [32][256][30]    = 960 KiB
  const size_t OFF_SC    = 102039552;              // f32  [32]
  const size_t NEED      = 102039680;
  if (ws_size < NEED) return;   // fail loudly (poison stays in d_out)

  char* ws = (char*)d_ws;
  u16*   xw     = (u16*)(ws + OFF_XW);
  float* hf     = (float*)(ws + OFF_HF);
  float* hb     = (float*)(ws + OFF_HB);
  float* h_db   = (float*)(ws + OFF_HDB);
  float* c_st   = (float*)(ws + OFF_C);
  float* feats  = (float*)(ws + OFF_FEATS);
  float* scores = (float*)(ws + OFF_SC);

  k_init<<<128, 256, 0, stream>>>(h0, c0, h_db, c_st);

  k_gemm_xw<<<dim3(G4 / BN, 8192 / BM, 2), 256, 0, stream>>>(
      sent, emb, w_ih_f, w_ih_b, b_ih_f, b_hh_f, b_ih_b, b_hh_b, xw);

  for (int t = 0; t < S_LEN; ++t){
    const float* hp = h_db + (size_t)(t & 1) * (2 * B * H);
    float*       hn = h_db + (size_t)((t + 1) & 1) * (2 * B * H);
    k_lstm_step<<<256, 256, 0, stream>>>(w_hh_f, w_hh_b, xw, hp, hn, c_st, hf, hb, t);
  }

  k_feats<<<S_LEN * B, 128, 0, stream>>>(hf, hb, w_out, b_out, feats);
  k_crf<<<B, 64, 0, stream>>>(feats, trans, tags, scores);
  k_final<<<1, 64, 0, stream>>>(scores, (float*)d_out);
}

// Round 2
// 1993.618 us; speedup vs baseline: 1.5306x; 1.5306x over previous
//
#include <hip/hip_runtime.h>
#include <hip/hip_bf16.h>
#include <math.h>

#define S_LEN 256
#define B 32
#define E 512
#define H 512
#define G4 2048          // 4*H
#define T_TAGS 30
#define START_TAG 28
#define STOP_TAG 29

typedef unsigned short u16;
typedef unsigned int   u32;
typedef __attribute__((ext_vector_type(8))) short bf16x8;
typedef __attribute__((ext_vector_type(4))) float f32x4;

__device__ __forceinline__ float bf2f(u16 u){
  u32 x = ((u32)u) << 16;
  return __uint_as_float(x);
}
__device__ __forceinline__ u16 f2bf(float f){
  u32 x = __float_as_uint(f);
  u32 r = (x + 0x7fffu + ((x >> 16) & 1u)) >> 16;
  return (u16)r;
}
__device__ __forceinline__ float sigf(float x){
  return 1.0f / (1.0f + __expf(-x));
}
__device__ __forceinline__ float tanh_fast(float x){
  return 1.0f - 2.0f / (__expf(2.0f * x) + 1.0f);
}

// ---------------- prep: gather + f32->bf16 for A (emb rows) ----------------
__global__ __launch_bounds__(256) void k_prep_a(
    const int* __restrict__ sent, const float* __restrict__ emb,
    u16* __restrict__ a16)
{
  int g = (blockIdx.x * 256 + threadIdx.x) * 8;      // < 8192*512
  int token = g >> 9, k = g & 511;
  const float* src = emb + (size_t)sent[token] * E + k;
  float4 v0 = *reinterpret_cast<const float4*>(src);
  float4 v1 = *reinterpret_cast<const float4*>(src + 4);
  u16 o[8];
  o[0]=f2bf(v0.x); o[1]=f2bf(v0.y); o[2]=f2bf(v0.z); o[3]=f2bf(v0.w);
  o[4]=f2bf(v1.x); o[5]=f2bf(v1.y); o[6]=f2bf(v1.z); o[7]=f2bf(v1.w);
  *reinterpret_cast<uint4*>(a16 + g) = *reinterpret_cast<const uint4*>(o);
}

// ---------------- prep: generic f32 -> bf16 (n = grid*256*8 exactly) ----------------
__global__ __launch_bounds__(256) void k_cvt(const float* __restrict__ src, u16* __restrict__ dst){
  int g = (blockIdx.x * 256 + threadIdx.x) * 8;
  float4 v0 = *reinterpret_cast<const float4*>(src + g);
  float4 v1 = *reinterpret_cast<const float4*>(src + g + 4);
  u16 o[8];
  o[0]=f2bf(v0.x); o[1]=f2bf(v0.y); o[2]=f2bf(v0.z); o[3]=f2bf(v0.w);
  o[4]=f2bf(v1.x); o[5]=f2bf(v1.y); o[6]=f2bf(v1.z); o[7]=f2bf(v1.w);
  *reinterpret_cast<uint4*>(dst + g) = *reinterpret_cast<const uint4*>(o);
}

// ---------------- init: h0 -> bf16 parity0, c0 -> c ----------------
__global__ __launch_bounds__(256) void k_init16(
    const float* __restrict__ h0, const float* __restrict__ c0,
    u16* __restrict__ h16, float* __restrict__ c_st)
{
  int g = (blockIdx.x * 256 + threadIdx.x) * 8;      // < 2*B*H = 32768
  float4 v0 = *reinterpret_cast<const float4*>(h0 + g);
  float4 v1 = *reinterpret_cast<const float4*>(h0 + g + 4);
  u16 o[8];
  o[0]=f2bf(v0.x); o[1]=f2bf(v0.y); o[2]=f2bf(v0.z); o[3]=f2bf(v0.w);
  o[4]=f2bf(v1.x); o[5]=f2bf(v1.y); o[6]=f2bf(v1.z); o[7]=f2bf(v1.w);
  *reinterpret_cast<uint4*>(h16 + g) = *reinterpret_cast<const uint4*>(o);
  *reinterpret_cast<float4*>(c_st + g)     = *reinterpret_cast<const float4*>(c0 + g);
  *reinterpret_cast<float4*>(c_st + g + 4) = *reinterpret_cast<const float4*>(c0 + g + 4);
}

// ---------------- phase A: xw = A16 @ W16^T + bias  (bf16 MFMA, 128x128 tile) ----------------
__global__ __launch_bounds__(256) void k_gemm_xw16(
    const u16* __restrict__ a16, const u16* __restrict__ w16ih,
    const float* __restrict__ b_ih_f, const float* __restrict__ b_hh_f,
    const float* __restrict__ b_ih_b, const float* __restrict__ b_hh_b,
    u16* __restrict__ xw)
{
  int dir = blockIdx.z;
  int n0 = blockIdx.x * 128;
  int m0 = blockIdx.y * 128;
  const u16* Wp = w16ih + (size_t)dir * G4 * E;
  const float* bi = dir ? b_ih_b : b_ih_f;
  const float* bh = dir ? b_hh_b : b_hh_f;
  int tid = threadIdx.x;

  __shared__ u16 As[128 * 32];
  __shared__ u16 Bs[128 * 32];

  int l  = tid & 63;
  int wid = tid >> 6;
  int wr = wid >> 1, wc = wid & 1;       // 2x2 wave grid, each wave 64x64
  int lr = l & 15, lh = l >> 4;
  int swzr = (lh ^ (lr & 3)) << 3;       // element offset of the 8-elem k-slice

  f32x4 acc[4][4];
  #pragma unroll
  for (int i = 0; i < 4; ++i)
    #pragma unroll
    for (int j = 0; j < 4; ++j)
      acc[i][j] = (f32x4){0.f, 0.f, 0.f, 0.f};

  for (int kt = 0; kt < E; kt += 32){
    __syncthreads();
    #pragma unroll
    for (int it = 0; it < 2; ++it){
      int u = it * 256 + tid;            // 0..511 (16B units)
      int row = u >> 2, c = u & 3;
      int sw = (c ^ (row & 3)) << 3;
      *reinterpret_cast<uint4*>(&As[row * 32 + sw]) =
        *reinterpret_cast<const uint4*>(a16 + (size_t)(m0 + row) * E + kt + c * 8);
      *reinterpret_cast<uint4*>(&Bs[row * 32 + sw]) =
        *reinterpret_cast<const uint4*>(Wp + (size_t)(n0 + row) * E + kt + c * 8);
    }
    __syncthreads();
    bf16x8 a[4], b[4];
    #pragma unroll
    for (int mi = 0; mi < 4; ++mi)
      a[mi] = *reinterpret_cast<const bf16x8*>(&As[(wr * 64 + mi * 16 + lr) * 32 + swzr]);
    #pragma unroll
    for (int ni = 0; ni < 4; ++ni)
      b[ni] = *reinterpret_cast<const bf16x8*>(&Bs[(wc * 64 + ni * 16 + lr) * 32 + swzr]);
    #pragma unroll
    for (int mi = 0; mi < 4; ++mi)
      #pragma unroll
      for (int ni = 0; ni < 4; ++ni)
        acc[mi][ni] = __builtin_amdgcn_mfma_f32_16x16x32_bf16(a[mi], b[ni], acc[mi][ni], 0, 0, 0);
  }

  // epilogue: +bias, bf16, scattered 2B stores (4 rows x 16 cols per (mi,ni,r))
  #pragma unroll
  for (int ni = 0; ni < 4; ++ni){
    int n = n0 + wc * 64 + ni * 16 + lr;
    float bias = bi[n] + bh[n];
    #pragma unroll
    for (int mi = 0; mi < 4; ++mi){
      #pragma unroll
      for (int r = 0; r < 4; ++r){
        int m = m0 + wr * 64 + mi * 16 + lh * 4 + r;
        xw[((size_t)dir * 8192 + m) * G4 + n] = f2bf(acc[mi][ni][r] + bias);
      }
    }
  }
}

// ---------------- phase B: one LSTM step, MFMA, 1 wave per block ----------------
// 256 blocks: dir = bx>>7, slice = bx&127 -> j0 = slice*4 (16 gate rows: g*512+j0+jr)
__global__ __launch_bounds__(64) void k_step16(
    const u16* __restrict__ w16hh, const u16* __restrict__ xw,
    const u16* __restrict__ h16p, u16* __restrict__ h16n,
    float* __restrict__ c_st, u16* __restrict__ hseq, int t)
{
  __shared__ float g_s[32][17];

  int bx = blockIdx.x;
  int dir = bx >> 7;
  int j0 = (bx & 127) << 2;
  int l = threadIdx.x;
  int lr = l & 15, lh = l >> 4;

  int g  = lr >> 2, jr = lr & 3;
  const u16* wrow = w16hh + (size_t)dir * (G4 * H) + (size_t)((g << 9) + j0 + jr) * H + lh * 8;
  const u16* arow = h16p + (size_t)dir * (B * H) + (size_t)lr * H + lh * 8;

  f32x4 acc0 = {0.f,0.f,0.f,0.f}, acc1 = {0.f,0.f,0.f,0.f};
  #pragma unroll 4
  for (int kt = 0; kt < 16; ++kt){
    bf16x8 bv = *reinterpret_cast<const bf16x8*>(wrow + kt * 32);
    bf16x8 a0 = *reinterpret_cast<const bf16x8*>(arow + kt * 32);
    bf16x8 a1 = *reinterpret_cast<const bf16x8*>(arow + 16 * H + kt * 32);
    acc0 = __builtin_amdgcn_mfma_f32_16x16x32_bf16(a0, bv, acc0, 0, 0, 0);
    acc1 = __builtin_amdgcn_mfma_f32_16x16x32_bf16(a1, bv, acc1, 0, 0, 0);
  }
  #pragma unroll
  for (int r = 0; r < 4; ++r){
    g_s[lh * 4 + r][lr] = acc0[r];
    g_s[16 + lh * 4 + r][lr] = acc1[r];
  }
  __syncthreads();

  int s_eff = dir ? (S_LEN - 1 - t) : t;
  #pragma unroll
  for (int pp = 0; pp < 2; ++pp){
    int p = pp * 64 + l;           // 0..127 : b = p>>2, jr2 = p&3
    int b = p >> 2, jr2 = p & 3;
    int j = j0 + jr2;
    const u16* xwp = xw + ((size_t)dir * 8192 + (size_t)s_eff * B + b) * G4;
    float iv = g_s[b][jr2]      + bf2f(xwp[j]);
    float fv = g_s[b][4 + jr2]  + bf2f(xwp[512 + j]);
    float gv = g_s[b][8 + jr2]  + bf2f(xwp[1024 + j]);
    float ov = g_s[b][12 + jr2] + bf2f(xwp[1536 + j]);
    size_t cidx = ((size_t)dir * B + b) * H + j;
    float c_old = c_st[cidx];
    float cn = sigf(fv) * c_old + sigf(iv) * tanh_fast(gv);
    float hn = sigf(ov) * tanh_fast(cn);
    c_st[cidx] = cn;
    u16 hb16 = f2bf(hn);
    h16n[cidx] = hb16;
    hseq[((size_t)dir * 8192 + (size_t)s_eff * B + b) * H + j] = hb16;
  }
}

// ---------------- phase C: feats[b][s][t] = [hf;hb] . w_out[t] + b_out[t] ----------------
// 256 blocks x 32 tokens; token rows staged fp32 in LDS
__global__ __launch_bounds__(256) void k_feats2(
    const u16* __restrict__ hseq, const float* __restrict__ w_out,
    const float* __restrict__ b_out, float* __restrict__ feats)
{
  __shared__ float row[32][1028];
  int blk = blockIdx.x;              // tokens m0 = blk*32
  int tid = threadIdx.x;
  const u16* hf16 = hseq;
  const u16* hb16 = hseq + (size_t)8192 * H;

  #pragma unroll
  for (int it = 0; it < 16; ++it){
    int u = it * 256 + tid;          // 0..4095 units of 8
    int flat = u * 8;
    int i = flat >> 10, d = flat & 1023;
    int m = blk * 32 + i;
    const u16* src = (d < 512) ? (hf16 + (size_t)m * H + d) : (hb16 + (size_t)m * H + d - 512);
    uint4 v = *reinterpret_cast<const uint4*>(src);
    float* dst = &row[i][d];
    dst[0] = bf2f((u16)(v.x & 0xffff)); dst[1] = bf2f((u16)(v.x >> 16));
    dst[2] = bf2f((u16)(v.y & 0xffff)); dst[3] = bf2f((u16)(v.y >> 16));
    dst[4] = bf2f((u16)(v.z & 0xffff)); dst[5] = bf2f((u16)(v.z >> 16));
    dst[6] = bf2f((u16)(v.w & 0xffff)); dst[7] = bf2f((u16)(v.w >> 16));
  }
  __syncthreads();

  int i = tid >> 3, tg = tid & 7;
  const float* w0 = w_out + (size_t)((tg + 0  < T_TAGS) ? tg + 0  : 0) * 1024;
  const float* w1 = w_out + (size_t)((tg + 8  < T_TAGS) ? tg + 8  : 0) * 1024;
  const float* w2 = w_out + (size_t)((tg + 16 < T_TAGS) ? tg + 16 : 0) * 1024;
  const float* w3 = w_out + (size_t)((tg + 24 < T_TAGS) ? tg + 24 : 0) * 1024;
  float s0 = 0.f, s1 = 0.f, s2 = 0.f, s3 = 0.f;
  #pragma unroll 4
  for (int k4 = 0; k4 < 256; ++k4){
    float4 rv = *reinterpret_cast<const float4*>(&row[i][k4 * 4]);
    float4 a = *reinterpret_cast<const float4*>(w0 + k4 * 4);
    float4 b = *reinterpret_cast<const float4*>(w1 + k4 * 4);
    float4 c = *reinterpret_cast<const float4*>(w2 + k4 * 4);
    float4 d = *reinterpret_cast<const float4*>(w3 + k4 * 4);
    s0 = fmaf(a.x,rv.x,s0); s0 = fmaf(a.y,rv.y,s0); s0 = fmaf(a.z,rv.z,s0); s0 = fmaf(a.w,rv.w,s0);
    s1 = fmaf(b.x,rv.x,s1); s1 = fmaf(b.y,rv.y,s1); s1 = fmaf(b.z,rv.z,s1); s1 = fmaf(b.w,rv.w,s1);
    s2 = fmaf(c.x,rv.x,s2); s2 = fmaf(c.y,rv.y,s2); s2 = fmaf(c.z,rv.z,s2); s2 = fmaf(c.w,rv.w,s2);
    s3 = fmaf(d.x,rv.x,s3); s3 = fmaf(d.y,rv.y,s3); s3 = fmaf(d.w,rv.w,s3); s3 = fmaf(d.z,rv.z,s3);
  }
  int m = blk * 32 + i;
  int s = m >> 5, b = m & 31;
  float* fp = feats + ((size_t)b * S_LEN + s) * T_TAGS;
  float sums[4] = {s0, s1, s2, s3};
  #pragma unroll
  for (int q = 0; q < 4; ++q){
    int tt = tg + q * 8;
    if (tt < T_TAGS) fp[tt] = sums[q] + b_out[tt];
  }
}

// ---------------- phase D: CRF forward + gold score, per batch element ----------------
__global__ __launch_bounds__(64) void k_crf(
    const float* __restrict__ feats, const float* __restrict__ trans,
    const int* __restrict__ tags, float* __restrict__ scores)
{
  int b = blockIdx.x;
  int tid = threadIdx.x;
  __shared__ float tr[T_TAGS][33];
  __shared__ float fv[32], fvn[32];
  for (int i = tid; i < T_TAGS * T_TAGS; i += 64) tr[i / T_TAGS][i % T_TAGS] = trans[i];
  if (tid < T_TAGS) fv[tid] = (tid == START_TAG) ? 0.f : -10000.f;
  __syncthreads();

  const float* fb = feats + (size_t)b * S_LEN * T_TAGS;
  for (int s = 0; s < S_LEN; ++s){
    if (tid < T_TAGS){
      float m = -1e30f;
      #pragma unroll
      for (int j = 0; j < T_TAGS; ++j) m = fmaxf(m, fv[j] + tr[tid][j]);
      float sum = 0.f;
      #pragma unroll
      for (int j = 0; j < T_TAGS; ++j) sum += __expf(fv[j] + tr[tid][j] - m);
      fvn[tid] = fb[s * T_TAGS + tid] + m + __logf(sum);
    }
    __syncthreads();
    if (tid < T_TAGS) fv[tid] = fvn[tid];
    __syncthreads();
  }

  float fsc = 0.f;
  if (tid == 0){
    float m = -1e30f;
    for (int i = 0; i < T_TAGS; ++i) m = fmaxf(m, fv[i] + tr[STOP_TAG][i]);
    float sum = 0.f;
    for (int i = 0; i < T_TAGS; ++i) sum += __expf(fv[i] + tr[STOP_TAG][i] - m);
    fsc = m + __logf(sum);
  }
  float g = 0.f;
  for (int s = tid; s < S_LEN; s += 64){
    int nxt = tags[s * B + b];
    int prv = (s == 0) ? START_TAG : tags[(s - 1) * B + b];
    g += tr[nxt][prv] + fb[s * T_TAGS + nxt];
  }
  #pragma unroll
  for (int o = 32; o > 0; o >>= 1) g += __shfl_down(g, o);
  if (tid == 0){
    int last = tags[(S_LEN - 1) * B + b];
    g += tr[STOP_TAG][last];
    scores[b] = fsc - g;
  }
}

__global__ void k_final(const float* __restrict__ scores, float* __restrict__ out){
  int tid = threadIdx.x;
  float v = (tid < B) ? scores[tid] : 0.f;
  #pragma unroll
  for (int o = 32; o > 0; o >>= 1) v += __shfl_down(v, o);
  if (tid == 0) out[0] = v;
}

// ---------------- host ----------------
extern "C" void kernel_launch(void* const* d_in, const int* in_sizes, int n_in,
                              void* d_out, int out_size, void* d_ws, size_t ws_size,
                              hipStream_t stream)
{
  const int*   sent   = (const int*)d_in[0];
  const int*   tags   = (const int*)d_in[1];
  const float* emb    = (const float*)d_in[2];
  const float* w_ih_f = (const float*)d_in[3];
  const float* w_hh_f = (const float*)d_in[4];
  const float* b_ih_f = (const float*)d_in[5];
  const float* b_hh_f = (const float*)d_in[6];
  const float* w_ih_b = (const float*)d_in[7];
  const float* w_hh_b = (const float*)d_in[8];
  const float* b_ih_b = (const float*)d_in[9];
  const float* b_hh_b = (const float*)d_in[10];
  const float* w_out  = (const float*)d_in[11];
  const float* b_out  = (const float*)d_in[12];
  const float* trans  = (const float*)d_in[13];
  const float* h0     = (const float*)d_in[14];
  const float* c0     = (const float*)d_in[15];

  // ws layout (bytes)
  const size_t OFF_XW   = 0;            // bf16 [2][8192][2048] = 64 MiB
  const size_t OFF_A16  = 67108864;     // bf16 [8192][512]     = 8 MiB
  const size_t OFF_WIH  = 75497472;     // bf16 [2][2048][512]  = 4 MiB
  const size_t OFF_WHH  = 79691776;     // bf16 [2][2048][512]  = 4 MiB
  const size_t OFF_HSEQ = 83886080;     // bf16 [2][8192][512]  = 16 MiB
  const size_t OFF_H16  = 100663296;    // bf16 [2][2][32][512] = 128 KiB (parity dbuf)
  const size_t OFF_C    = 100794368;    // f32  [2][32][512]    = 128 KiB
  const size_t OFF_FEATS= 100925440;    // f32  [32][256][30]   = 960 KiB
  const size_t OFF_SC   = 101908480;    // f32  [32]
  const size_t NEED     = 101908608;
  if (ws_size < NEED) return;

  char* ws = (char*)d_ws;
  u16*   xw     = (u16*)(ws + OFF_XW);
  u16*   a16    = (u16*)(ws + OFF_A16);
  u16*   w16ih  = (u16*)(ws + OFF_WIH);
  u16*   w16hh  = (u16*)(ws + OFF_WHH);
  u16*   hseq   = (u16*)(ws + OFF_HSEQ);
  u16*   h16    = (u16*)(ws + OFF_H16);
  float* c_st   = (float*)(ws + OFF_C);
  float* feats  = (float*)(ws + OFF_FEATS);
  float* scores = (float*)(ws + OFF_SC);

  k_prep_a<<<2048, 256, 0, stream>>>(sent, emb, a16);
  k_cvt<<<512, 256, 0, stream>>>(w_ih_f, w16ih);
  k_cvt<<<512, 256, 0, stream>>>(w_ih_b, w16ih + (size_t)G4 * E);
  k_cvt<<<512, 256, 0, stream>>>(w_hh_f, w16hh);
  k_cvt<<<512, 256, 0, stream>>>(w_hh_b, w16hh + (size_t)G4 * H);
  k_init16<<<16, 256, 0, stream>>>(h0, c0, h16, c_st);

  k_gemm_xw16<<<dim3(G4 / 128, 8192 / 128, 2), 256, 0, stream>>>(
      a16, w16ih, b_ih_f, b_hh_f, b_ih_b, b_hh_b, xw);

  const size_t HPAR = 2 * B * H;
  for (int t = 0; t < S_LEN; ++t){
    const u16* hp = h16 + (size_t)(t & 1) * HPAR;
    u16*       hn = h16 + (size_t)((t + 1) & 1) * HPAR;
    k_step16<<<256, 64, 0, stream>>>(w16hh, xw, hp, hn, c_st, hseq, t);
  }

  k_feats2<<<256, 256, 0, stream>>>(hseq, w_out, b_out, feats);
  k_crf<<<B, 64, 0, stream>>>(feats, trans, tags, scores);
  k_final<<<1, 64, 0, stream>>>(scores, (float*)d_out);
}